// Round 10
// baseline (110.000 us; speedup 1.0000x reference)
//
#include <hip/hip_runtime.h>

#define NATOMS 16

// LUT: unordered pair slot s in [0,120) -> (j<<4)|k, j<k in [0,16)
struct TriTab {
    unsigned char v[120];
    constexpr TriTab() : v() {
        int s = 0;
        for (int j = 0; j < 15; ++j)
            for (int k = j + 1; k < 16; ++k)
                v[s++] = (unsigned char)((j << 4) | k);
    }
};
__constant__ TriTab TRI = TriTab();

// DIAGNOSTIC BUILD: body repeated REPS times with an opaque zero bias so the
// compiler must re-execute compute+stores each rep (outputs identical).
// Purpose: push aev above the 41-us fill dispatches into rocprof top-5.
#define REPS 5

__global__ __launch_bounds__(64, 8) void aev_kernel(const int* __restrict__ species,
                                                    const float* __restrict__ coords,
                                                    float* __restrict__ out,
                                                    int nmol) {
    const int l = threadIdx.x;
    const int bid = blockIdx.x;
    const int b = bid >> 4;              // molecule
    const int i = bid & 15;              // center atom

    __shared__ float scm[48];
    __shared__ int   ssp[16];
    __shared__ float rad[16][17];
    __shared__ int   hist[10], sBase[10], sCur[10];
    __shared__ float4 ebuf[105];

    const unsigned jk0 = TRI.v[l];
    const unsigned jk1 = (l < 56) ? TRI.v[64 + l] : 0u;

    if (l < 48) scm[l] = coords[b * 48 + l];
    if (l < 16) {
        int sp = species[b * 16 + l];
        ssp[l] = sp;
        if (i == 0) out[b * 16 + l] = (float)sp;
    }

    const int f = l & 31;
    const int z = f & 7, a = f >> 3;
    const float ang = (2.0f * (float)z + 1.0f) * 0.19634954084936207f;
    const float czh = 0.5f * __cosf(ang);
    const float szh = 0.5f * __sinf(ang);
    const float ga  = __expf(-3.38f * (float)(a * a - a));
    __syncthreads();

    const int spi = ssp[i];
    float* base_o = out + (size_t)nmol * 16 + (size_t)(b * 16 + i) * 384;

    #pragma unroll 1
    for (int rep = 0; rep < REPS; ++rep) {
        // opaque zero: defeats LICM across reps; runtime value is 0.0f
        float bias = 0.0f;
        asm volatile("" : "+v"(bias));

        if (l < 10) hist[l] = 0;
        const float xi = scm[3 * i] + bias, yi = scm[3 * i + 1], zi = scm[3 * i + 2];
        __syncthreads();

        auto pairq = [&](int jj, float& dx, float& dy, float& dz, float& d, float& fca) {
            dx = xi - scm[3 * jj]; dy = yi - scm[3 * jj + 1]; dz = zi - scm[3 * jj + 2];
            bool pv = (jj != i) && (spi >= 0) && (ssp[jj] >= 0);
            float d2 = dx * dx + dy * dy + dz * dz;
            d = sqrtf(pv ? d2 : 1.0f);
            fca = (pv && d <= 3.5f) ? fmaf(0.5f, __cosf(d * 0.8975979010256552f), 0.5f) : 0.0f;
        };

        float ca0 = 0.f, sa0 = 0.f, t00 = 0.f, r10 = 0.f; int p0 = -1;
        {
            const int j = jk0 >> 4, k = jk0 & 15;
            float dxj, dyj, dzj, dj, fcaj, dxk, dyk, dzk, dk, fcak;
            pairq(j, dxj, dyj, dzj, dj, fcaj);
            pairq(k, dxk, dyk, dzk, dk, fcak);
            if (fcaj > 0.0f && fcak > 0.0f) {
                float dot = dxj * dxk + dyj * dyk + dzj * dzk;
                float ca = __fdividef(0.95f * dot, dj * dk);
                ca = fminf(0.95f, fmaxf(-0.95f, ca));
                sa0 = sqrtf(1.0f - ca * ca);
                ca0 = ca;
                float davg = 0.5f * (dj + dk);
                float e0 = davg - 0.9f;
                t00 = 2.0f * fcaj * fcak * __expf(-8.0f * e0 * e0);
                r10 = __expf(10.4f * davg - 12.74f);
                int sj = ssp[j], sk = ssp[k];
                int lo = sj < sk ? sj : sk, hi = sj < sk ? sk : sj;
                p0 = lo * 4 + hi - ((lo * (lo + 1)) >> 1);
                atomicAdd(&hist[p0], 1);
            }
        }

        float ca1 = 0.f, sa1 = 0.f, t01 = 0.f, r11 = 0.f; int p1 = -1;
        if (l < 56) {
            const int j = jk1 >> 4, k = jk1 & 15;
            float dxj, dyj, dzj, dj, fcaj, dxk, dyk, dzk, dk, fcak;
            pairq(j, dxj, dyj, dzj, dj, fcaj);
            pairq(k, dxk, dyk, dzk, dk, fcak);
            if (fcaj > 0.0f && fcak > 0.0f) {
                float dot = dxj * dxk + dyj * dyk + dzj * dzk;
                float ca = __fdividef(0.95f * dot, dj * dk);
                ca = fminf(0.95f, fmaxf(-0.95f, ca));
                sa1 = sqrtf(1.0f - ca * ca);
                ca1 = ca;
                float davg = 0.5f * (dj + dk);
                float e0 = davg - 0.9f;
                t01 = 2.0f * fcaj * fcak * __expf(-8.0f * e0 * e0);
                r11 = __expf(10.4f * davg - 12.74f);
                int sj = ssp[j], sk = ssp[k];
                int lo = sj < sk ? sj : sk, hi = sj < sk ? sk : sj;
                p1 = lo * 4 + hi - ((lo * (lo + 1)) >> 1);
                atomicAdd(&hist[p1], 1);
            }
        }

        {
            const int jj = l & 15, rg = l >> 4;
            float dx = xi - scm[3 * jj], dy = yi - scm[3 * jj + 1], dz = zi - scm[3 * jj + 2];
            bool pv = (jj != i) && (spi >= 0) && (ssp[jj] >= 0);
            float d = sqrtf(dx * dx + dy * dy + dz * dz);
            float fcr4 = (pv && d <= 5.2f)
                       ? 0.25f * fmaf(0.5f, __cosf(d * 0.6041515809446141f), 0.5f) : 0.0f;
            #pragma unroll
            for (int rr = 0; rr < 4; ++rr) {
                int r = rg * 4 + rr;
                float e = d - (0.9f + 0.26875f * (float)r);
                rad[jj][r] = fcr4 * __expf(-16.0f * e * e);
            }
        }
        __syncthreads();

        if (l < 10) {
            int sum = 0;
            for (int qq = 0; qq < l; ++qq) sum += hist[qq];
            sBase[l] = sum;
            sCur[l] = sum;
        }
        __syncthreads();

        if (p0 >= 0) { int idx = atomicAdd(&sCur[p0], 1); ebuf[idx] = make_float4(ca0, sa0, t00, r10); }
        if (p1 >= 0) { int idx = atomicAdd(&sCur[p1], 1); ebuf[idx] = make_float4(ca1, sa1, t01, r11); }
        __syncthreads();

        {
            const int half = l >> 5;
            const bool a1 = (a & 1), a2 = (a & 2) != 0;
            #pragma unroll
            for (int pp = 0; pp < 5; ++pp) {
                int p = pp * 2 + half;
                int st = sBase[p];
                int n = hist[p];
                float acc = 0.0f;
                for (int e = 0; e < n; ++e) {
                    float4 v = ebuf[st + e];
                    float c1 = fmaf(czh, v.x, fmaf(szh, v.y, 0.5f));
                    float c2 = c1 * c1;
                    float c4 = c2 * c2;
                    float c8 = c4 * c4;
                    float c16 = c8 * c8;
                    float c32 = c16 * c16;
                    float tt = v.z;
                    float rsq = v.w * v.w;
                    tt = a1 ? tt * v.w : tt;
                    tt = a2 ? tt * rsq : tt;
                    acc = fmaf(tt, c32, acc);
                }
                base_o[64 + p * 32 + f] = acc * ga;
            }
        }

        {
            const int s_ = l >> 4, r_ = l & 15;
            float rv = 0.0f;
            #pragma unroll
            for (int jj = 0; jj < 16; ++jj)
                rv += (ssp[jj] == s_) ? rad[jj][r_] : 0.0f;
            base_o[l] = rv;
        }
        __syncthreads();
    }
}

extern "C" void kernel_launch(void* const* d_in, const int* in_sizes, int n_in,
                              void* d_out, int out_size, void* d_ws, size_t ws_size,
                              hipStream_t stream) {
    const int*   species = (const int*)d_in[0];
    const float* coords  = (const float*)d_in[1];
    float*       out     = (float*)d_out;
    int nmol = in_sizes[0] / NATOMS;   // 512
    aev_kernel<<<nmol * 16, 64, 0, stream>>>(species, coords, out, nmol);
}

// Round 11
// 68.092 us; speedup vs baseline: 1.6155x; 1.6155x over previous
//
#include <hip/hip_runtime.h>

// One block = 4 centers of one molecule: grid = nmol*4, 256 threads = 4 waves.
// Wave w owns center i = (blockIdx&3)*4 + w.
__global__ __launch_bounds__(256, 8) void aev_kernel(const int* __restrict__ species,
                                                     const float* __restrict__ coords,
                                                     float* __restrict__ out,
                                                     int nmol) {
    const int t = threadIdx.x;
    const int w = t >> 6;            // wave 0..3
    const int l = t & 63;            // lane
    const int bid = blockIdx.x;
    const int b = bid >> 2;          // molecule
    const int g = bid & 3;
    const int i = g * 4 + w;         // center atom

    __shared__ float  scm[48];
    __shared__ int    ssp[16];
    __shared__ float4 pd[4][16];     // dx, dy, dz, d
    __shared__ float4 pf[4][16];     // rinv, fca, fcr4, 0
    __shared__ float  rad[4][16][17];
    __shared__ int    vlist[4][16];  // j | (sp<<4), compacted valid pairs
    __shared__ int    hist[4][10], sBase[4][10], sCur[4][10];
    __shared__ float4 ebuf[4][105];  // ca, sa, t0, r1

    // ---- setup ----
    if (t < 48) scm[t] = coords[b * 48 + t];
    if (t < 16) {
        int sp = species[b * 16 + t];
        ssp[t] = sp;
        if (g == 0) out[b * 16 + t] = (float)sp;   // species output (as float)
    }
    if (l < 10) hist[w][l] = 0;

    const int f = l & 31, z = f & 7, a = f >> 3;
    const float ang = (2.0f * (float)z + 1.0f) * 0.19634954084936207f;  // (2z+1)*pi/16
    const float czh = 0.5f * __cosf(ang);
    const float szh = 0.5f * __sinf(ang);
    const float ga  = __expf(-3.38f * (float)(a * a - a));
    __syncthreads();   // scm/ssp visible

    const int spi = ssp[i];
    const float xi = scm[3 * i], yi = scm[3 * i + 1], zi = scm[3 * i + 2];

    // ---- pair phase (lanes 0..15): compute once, stage in LDS ----
    int  spl = 0;
    bool pvalid = false;
    if (l < 16) {
        spl = ssp[l];
        float dx = xi - scm[3 * l], dy = yi - scm[3 * l + 1], dz = zi - scm[3 * l + 2];
        bool pv = (l != i) && (spi >= 0) && (spl >= 0);
        float d2 = dx * dx + dy * dy + dz * dz;
        float d2s = pv ? d2 : 1.0f;
        float rinv = __frsqrt_rn(d2s);
        float d = d2s * rinv;
        float fca  = (pv && d <= 3.5f) ? fmaf(0.5f, __cosf(d * 0.8975979010256552f), 0.5f) : 0.0f;
        float fcr4 = (pv && d <= 5.2f) ? 0.25f * fmaf(0.5f, __cosf(d * 0.6041515809446141f), 0.5f) : 0.0f;
        pd[w][l] = make_float4(dx, dy, dz, d);
        pf[w][l] = make_float4(rinv, fca, fcr4, 0.0f);
        pvalid = fca > 0.0f;
    }
    // compact valid-pair list (wave-level ballot; bits 0..15 only)
    const unsigned long long vm = __ballot(pvalid);
    const int V = __popcll(vm);
    if (pvalid) {
        int idx = __popcll(vm & ((1ull << l) - 1ull));
        vlist[w][idx] = l | (spl << 4);
    }
    // species masks for radial gather (wave-uniform)
    const unsigned m0 = (unsigned)__ballot(l < 16 && spl == 0);
    const unsigned m1 = (unsigned)__ballot(l < 16 && spl == 1);
    const unsigned m2 = (unsigned)__ballot(l < 16 && spl == 2);
    const unsigned m3 = (unsigned)__ballot(l < 16 && spl == 3);
    __syncthreads();   // pd/pf/vlist visible

    // ---- radial staging: rad[w][jj][r] (64 lanes = 16 j x 4 r-groups) ----
    {
        const int jj = l & 15, rg = l >> 4;
        float d = pd[w][jj].w;
        float fcr4 = pf[w][jj].z;
        #pragma unroll
        for (int rr = 0; rr < 4; ++rr) {
            int r = rg * 4 + rr;
            float e = d - (0.9f + 0.26875f * (float)r);
            rad[w][jj][r] = fcr4 * __expf(-16.0f * e * e);
        }
    }

    // ---- triple phase over compacted pairs: nt = V*(V-1)/2 slots ----
    const int nt = (V * (V - 1)) >> 1;
    const int tw = 2 * V - 1;
    float ca0 = 0.f, sa0 = 0.f, t00 = 0.f, r10 = 0.f; int p0 = -1;
    float ca1 = 0.f, sa1 = 0.f, t01 = 0.f, r11 = 0.f; int p1 = -1;
    #pragma unroll
    for (int slot = 0; slot < 2; ++slot) {
        const int s = slot == 0 ? l : (64 + l);
        if (s < nt) {
            // decode a<b over V entries; boundary discriminants are perfect squares
            float disc = (float)(tw * tw - 8 * s);
            int aa = (int)floorf(0.5f * ((float)tw - sqrtf(disc)));
            aa = aa < 0 ? 0 : (aa > V - 2 ? V - 2 : aa);
            int offa = (aa * (2 * V - 1 - aa)) >> 1;
            if (s < offa) { --aa; offa = (aa * (2 * V - 1 - aa)) >> 1; }
            else { int offn = ((aa + 1) * (2 * V - 2 - aa)) >> 1; if (s >= offn) { ++aa; offa = offn; } }
            const int bb = aa + 1 + (s - offa);
            const int va = vlist[w][aa], vb = vlist[w][bb];
            const int j = va & 15, spj = va >> 4;
            const int k = vb & 15, spk = vb >> 4;
            float4 Pj = pd[w][j], Pk = pd[w][k];
            float4 Fj = pf[w][j], Fk = pf[w][k];
            float dot = Pj.x * Pk.x + Pj.y * Pk.y + Pj.z * Pk.z;
            float ca = 0.95f * dot * Fj.x * Fk.x;
            ca = fminf(0.95f, fmaxf(-0.95f, ca));
            float s2 = 1.0f - ca * ca;                 // >= 0.0975
            float sa = s2 * __frsqrt_rn(s2);
            float davg = 0.5f * (Pj.w + Pk.w);
            float e0 = davg - 0.9f;
            float t0 = 2.0f * Fj.y * Fk.y * __expf(-8.0f * e0 * e0);
            float r1 = __expf(10.4f * davg - 12.74f);
            int lo = spj < spk ? spj : spk, hi = spj < spk ? spk : spj;
            int p = lo * 4 + hi - ((lo * (lo + 1)) >> 1);
            atomicAdd(&hist[w][p], 1);
            if (slot == 0) { ca0 = ca; sa0 = sa; t00 = t0; r10 = r1; p0 = p; }
            else           { ca1 = ca; sa1 = sa; t01 = t0; r11 = r1; p1 = p; }
        }
    }
    __syncthreads();   // hist complete

    // ---- exclusive prefix over 10 buckets ----
    if (l < 10) {
        int sum = 0;
        for (int qq = 0; qq < l; ++qq) sum += hist[w][qq];
        sBase[w][l] = sum;
        sCur[w][l] = sum;
    }
    __syncthreads();

    // ---- bucket fill ----
    if (p0 >= 0) { int idx = atomicAdd(&sCur[w][p0], 1); ebuf[w][idx] = make_float4(ca0, sa0, t00, r10); }
    if (p1 >= 0) { int idx = atomicAdd(&sCur[w][p1], 1); ebuf[w][idx] = make_float4(ca1, sa1, t01, r11); }
    __syncthreads();

    // ---- phase B: angular gather; lane = (p-half, f) ----
    float* base_o = out + (size_t)nmol * 16 + (size_t)(b * 16 + i) * 384;
    {
        const int half = l >> 5;
        const bool a1 = (a & 1), a2 = (a & 2) != 0;
        #pragma unroll
        for (int pp = 0; pp < 5; ++pp) {
            int p = pp * 2 + half;
            int st = sBase[w][p];
            int n = hist[w][p];
            float acc = 0.0f;
            for (int e = 0; e < n; ++e) {
                float4 v = ebuf[w][st + e];
                float c1 = fmaf(czh, v.x, fmaf(szh, v.y, 0.5f));  // (1+cos(th-shfz))/2
                float c2 = c1 * c1;
                float c4 = c2 * c2;
                float c8 = c4 * c4;
                float c16 = c8 * c8;
                float c32 = c16 * c16;
                float tt = v.z;
                float rsq = v.w * v.w;
                tt = a1 ? tt * v.w : tt;
                tt = a2 ? tt * rsq : tt;                           // tt = t0 * r1^a
                acc = fmaf(tt, c32, acc);
            }
            base_o[64 + p * 32 + f] = acc * ga;
        }
    }

    // ---- phase R: radial gather over species-mask bits ----
    {
        const int s_ = l >> 4, r_ = l & 15;
        unsigned m = s_ < 2 ? (s_ == 0 ? m0 : m1) : (s_ == 2 ? m2 : m3);
        float rv = 0.0f;
        while (m) {
            int jj = __ffs(m) - 1;
            m &= m - 1;
            rv += rad[w][jj][r_];
        }
        base_o[l] = rv;
    }
}

extern "C" void kernel_launch(void* const* d_in, const int* in_sizes, int n_in,
                              void* d_out, int out_size, void* d_ws, size_t ws_size,
                              hipStream_t stream) {
    const int*   species = (const int*)d_in[0];
    const float* coords  = (const float*)d_in[1];
    float*       out     = (float*)d_out;
    int nmol = in_sizes[0] / 16;   // 512
    aev_kernel<<<nmol * 4, 256, 0, stream>>>(species, coords, out, nmol);
}

// Round 12
// 68.091 us; speedup vs baseline: 1.6155x; 1.0000x over previous
//
#include <hip/hip_runtime.h>

// One block = 4 centers of one molecule: grid = nmol*4, 256 threads = 4 waves.
// Wave w owns center i = (blockIdx&3)*4 + w. ALL inter-phase state is
// wave-private ([w]-indexed LDS), so there are NO block barriers: same-wave
// ds_write -> ds_read ordering is guaranteed by compiler-inserted lgkmcnt.
__global__ __launch_bounds__(256, 8) void aev_kernel(const int* __restrict__ species,
                                                     const float* __restrict__ coords,
                                                     float* __restrict__ out,
                                                     int nmol) {
    const int t = threadIdx.x;
    const int w = t >> 6;            // wave 0..3
    const int l = t & 63;            // lane
    const int bid = blockIdx.x;
    const int b = bid >> 2;          // molecule
    const int g = bid & 3;
    const int i = g * 4 + w;         // center atom

    __shared__ float  scm[4][48];    // per-wave coord copy
    __shared__ int    ssp[4][16];    // per-wave species copy
    __shared__ float4 pd[4][16];     // dx, dy, dz, d
    __shared__ float4 pf[4][16];     // rinv, fca, fcr4, 0
    __shared__ float  rad[4][16][17];
    __shared__ int    vlist[4][16];  // j | (sp<<4), compacted valid pairs
    __shared__ int    hist[4][10], sBase[4][10], sCur[4][10];
    __shared__ float4 ebuf[4][105];  // ca, sa, t0, r1

    // ---- per-wave setup (no cross-wave dependencies) ----
    if (l < 48) scm[w][l] = coords[b * 48 + l];
    if (l < 16) {
        int sp = species[b * 16 + l];
        ssp[w][l] = sp;
        if (g == 0 && w == 0) out[b * 16 + l] = (float)sp;   // species output (as float)
    }
    if (l < 10) hist[w][l] = 0;

    const int f = l & 31, z = f & 7, a = f >> 3;
    const float ang = (2.0f * (float)z + 1.0f) * 0.19634954084936207f;  // (2z+1)*pi/16
    const float czh = 0.5f * __cosf(ang);
    const float szh = 0.5f * __sinf(ang);
    const float ga  = __expf(-3.38f * (float)(a * a - a));

    const int spi = ssp[w][i];
    const float xi = scm[w][3 * i], yi = scm[w][3 * i + 1], zi = scm[w][3 * i + 2];

    // ---- pair phase (lanes 0..15): compute once, stage in LDS ----
    int  spl = 0;
    bool pvalid = false;
    if (l < 16) {
        spl = ssp[w][l];
        float dx = xi - scm[w][3 * l], dy = yi - scm[w][3 * l + 1], dz = zi - scm[w][3 * l + 2];
        bool pv = (l != i) && (spi >= 0) && (spl >= 0);
        float d2 = dx * dx + dy * dy + dz * dz;
        float d2s = pv ? d2 : 1.0f;
        float rinv = __frsqrt_rn(d2s);
        float d = d2s * rinv;
        float fca  = (pv && d <= 3.5f) ? fmaf(0.5f, __cosf(d * 0.8975979010256552f), 0.5f) : 0.0f;
        float fcr4 = (pv && d <= 5.2f) ? 0.25f * fmaf(0.5f, __cosf(d * 0.6041515809446141f), 0.5f) : 0.0f;
        pd[w][l] = make_float4(dx, dy, dz, d);
        pf[w][l] = make_float4(rinv, fca, fcr4, 0.0f);
        pvalid = fca > 0.0f;
    }
    // compact valid-pair list (wave ballot; bits 0..15 only)
    const unsigned long long vm = __ballot(pvalid);
    const int V = __popcll(vm);
    if (pvalid) {
        int idx = __popcll(vm & ((1ull << l) - 1ull));
        vlist[w][idx] = l | (spl << 4);
    }
    // species masks for radial gather (wave-uniform)
    const unsigned m0 = (unsigned)__ballot(l < 16 && spl == 0);
    const unsigned m1 = (unsigned)__ballot(l < 16 && spl == 1);
    const unsigned m2 = (unsigned)__ballot(l < 16 && spl == 2);
    const unsigned m3 = (unsigned)__ballot(l < 16 && spl == 3);

    // ---- radial staging: rad[w][jj][r] (64 lanes = 16 j x 4 r-groups) ----
    {
        const int jj = l & 15, rg = l >> 4;
        float d = pd[w][jj].w;
        float fcr4 = pf[w][jj].z;
        #pragma unroll
        for (int rr = 0; rr < 4; ++rr) {
            int r = rg * 4 + rr;
            float e = d - (0.9f + 0.26875f * (float)r);
            rad[w][jj][r] = fcr4 * __expf(-16.0f * e * e);
        }
    }

    // ---- triple phase over compacted pairs: nt = V*(V-1)/2 slots ----
    const int nt = (V * (V - 1)) >> 1;
    const int tw = 2 * V - 1;
    float ca0 = 0.f, sa0 = 0.f, t00 = 0.f, r10 = 0.f; int p0 = -1;
    float ca1 = 0.f, sa1 = 0.f, t01 = 0.f, r11 = 0.f; int p1 = -1;
    #pragma unroll
    for (int slot = 0; slot < 2; ++slot) {
        const int s = slot == 0 ? l : (64 + l);
        if (s < nt) {
            // decode a<b over V entries; boundary discriminants are perfect squares
            float disc = (float)(tw * tw - 8 * s);
            int aa = (int)floorf(0.5f * ((float)tw - sqrtf(disc)));
            aa = aa < 0 ? 0 : (aa > V - 2 ? V - 2 : aa);
            int offa = (aa * (2 * V - 1 - aa)) >> 1;
            if (s < offa) { --aa; offa = (aa * (2 * V - 1 - aa)) >> 1; }
            else { int offn = ((aa + 1) * (2 * V - 2 - aa)) >> 1; if (s >= offn) { ++aa; offa = offn; } }
            const int bb = aa + 1 + (s - offa);
            const int va = vlist[w][aa], vb = vlist[w][bb];
            const int j = va & 15, spj = va >> 4;
            const int k = vb & 15, spk = vb >> 4;
            float4 Pj = pd[w][j], Pk = pd[w][k];
            float4 Fj = pf[w][j], Fk = pf[w][k];
            float dot = Pj.x * Pk.x + Pj.y * Pk.y + Pj.z * Pk.z;
            float ca = 0.95f * dot * Fj.x * Fk.x;
            ca = fminf(0.95f, fmaxf(-0.95f, ca));
            float s2 = 1.0f - ca * ca;                 // >= 0.0975
            float sa = s2 * __frsqrt_rn(s2);
            float davg = 0.5f * (Pj.w + Pk.w);
            float e0 = davg - 0.9f;
            float t0 = 2.0f * Fj.y * Fk.y * __expf(-8.0f * e0 * e0);
            float r1 = __expf(10.4f * davg - 12.74f);
            int lo = spj < spk ? spj : spk, hi = spj < spk ? spk : spj;
            int p = lo * 4 + hi - ((lo * (lo + 1)) >> 1);
            atomicAdd(&hist[w][p], 1);
            if (slot == 0) { ca0 = ca; sa0 = sa; t00 = t0; r10 = r1; p0 = p; }
            else           { ca1 = ca; sa1 = sa; t01 = t0; r11 = r1; p1 = p; }
        }
    }

    // ---- exclusive prefix over 10 buckets (wave-private) ----
    if (l < 10) {
        int sum = 0;
        for (int qq = 0; qq < l; ++qq) sum += hist[w][qq];
        sBase[w][l] = sum;
        sCur[w][l] = sum;
    }

    // ---- bucket fill ----
    if (p0 >= 0) { int idx = atomicAdd(&sCur[w][p0], 1); ebuf[w][idx] = make_float4(ca0, sa0, t00, r10); }
    if (p1 >= 0) { int idx = atomicAdd(&sCur[w][p1], 1); ebuf[w][idx] = make_float4(ca1, sa1, t01, r11); }

    // ---- phase B: angular gather; lane = (p-half, f) ----
    float* base_o = out + (size_t)nmol * 16 + (size_t)(b * 16 + i) * 384;
    {
        const int half = l >> 5;
        const bool a1 = (a & 1), a2 = (a & 2) != 0;
        #pragma unroll
        for (int pp = 0; pp < 5; ++pp) {
            int p = pp * 2 + half;
            int st = sBase[w][p];
            int n = hist[w][p];
            float acc = 0.0f;
            for (int e = 0; e < n; ++e) {
                float4 v = ebuf[w][st + e];
                float c1 = fmaf(czh, v.x, fmaf(szh, v.y, 0.5f));  // (1+cos(th-shfz))/2
                float c2 = c1 * c1;
                float c4 = c2 * c2;
                float c8 = c4 * c4;
                float c16 = c8 * c8;
                float c32 = c16 * c16;
                float tt = v.z;
                float rsq = v.w * v.w;
                tt = a1 ? tt * v.w : tt;
                tt = a2 ? tt * rsq : tt;                           // tt = t0 * r1^a
                acc = fmaf(tt, c32, acc);
            }
            base_o[64 + p * 32 + f] = acc * ga;
        }
    }

    // ---- phase R: radial gather over species-mask bits ----
    {
        const int s_ = l >> 4, r_ = l & 15;
        unsigned m = s_ < 2 ? (s_ == 0 ? m0 : m1) : (s_ == 2 ? m2 : m3);
        float rv = 0.0f;
        while (m) {
            int jj = __ffs(m) - 1;
            m &= m - 1;
            rv += rad[w][jj][r_];
        }
        base_o[l] = rv;
    }
}

extern "C" void kernel_launch(void* const* d_in, const int* in_sizes, int n_in,
                              void* d_out, int out_size, void* d_ws, size_t ws_size,
                              hipStream_t stream) {
    const int*   species = (const int*)d_in[0];
    const float* coords  = (const float*)d_in[1];
    float*       out     = (float*)d_out;
    int nmol = in_sizes[0] / 16;   // 512
    aev_kernel<<<nmol * 4, 256, 0, stream>>>(species, coords, out, nmol);
}

// Round 13
// 67.960 us; speedup vs baseline: 1.6186x; 1.0019x over previous
//
#include <hip/hip_runtime.h>

// Block = 256 threads = 4 waves; each 32-lane HALF-WAVE owns one center atom.
// Block covers 8 centers; grid = nmol*2. All inter-phase state is half-wave-
// private ([cb]-indexed LDS) -> NO block barriers needed (same-wave ds
// ordering is automatic; validated by R12).
__global__ __launch_bounds__(256, 4) void aev_kernel(const int* __restrict__ species,
                                                     const float* __restrict__ coords,
                                                     float* __restrict__ out,
                                                     int nmol) {
    const int t  = threadIdx.x;
    const int w  = t >> 6;           // wave 0..3
    const int l  = t & 63;           // lane in wave
    const int h  = l >> 5;           // half 0/1
    const int lh = l & 31;           // lane in half
    const int cb = w * 2 + h;        // center slot in block 0..7
    const int b  = blockIdx.x >> 1;  // molecule
    const int g  = blockIdx.x & 1;
    const int i  = g * 8 + cb;       // center atom 0..15

    __shared__ float  scm[4][48];    // per-wave coord copy
    __shared__ int    ssp[4][16];
    __shared__ float4 pd[8][16];     // dx,dy,dz,d         (per center)
    __shared__ float4 pf[8][16];     // rinv,fca,fcr4,0
    __shared__ float  rad[8][16][17];
    __shared__ int    vlist[8][16];
    __shared__ int    hist[8][10], sBase[8][10], sCur[8][10];
    __shared__ float4 ebuf[8][105];

    // ---- per-wave setup ----
    if (l < 48) scm[w][l] = coords[b * 48 + l];
    if (l < 16) {
        int sp = species[b * 16 + l];
        ssp[w][l] = sp;
        if (g == 0 && w == 0) out[b * 16 + l] = (float)sp;   // species (as float)
    }
    if (lh < 10) hist[cb][lh] = 0;

    // per-lane angular constants: lane lh owns feature f = lh (z = f&7, a = f>>3)
    const int z = lh & 7, a = lh >> 3;
    const float ang = (2.0f * (float)z + 1.0f) * 0.19634954084936207f;  // (2z+1)*pi/16
    const float czh = 0.5f * __cosf(ang);
    const float szh = 0.5f * __sinf(ang);
    const float ga  = __expf(-3.38f * (float)(a * a - a));

    const int spi = ssp[w][i];
    const float xi = scm[w][3 * i], yi = scm[w][3 * i + 1], zi = scm[w][3 * i + 2];

    // ---- pair phase (lanes lh<16 of each half) ----
    int  spl = 0;
    bool pvalid = false;
    if (lh < 16) {
        spl = ssp[w][lh];
        float dx = xi - scm[w][3 * lh], dy = yi - scm[w][3 * lh + 1], dz = zi - scm[w][3 * lh + 2];
        bool pv = (lh != i) && (spi >= 0) && (spl >= 0);
        float d2 = dx * dx + dy * dy + dz * dz;
        float d2s = pv ? d2 : 1.0f;
        float rinv = __frsqrt_rn(d2s);
        float d = d2s * rinv;
        float fca  = (pv && d <= 3.5f) ? fmaf(0.5f, __cosf(d * 0.8975979010256552f), 0.5f) : 0.0f;
        float fcr4 = (pv && d <= 5.2f) ? 0.25f * fmaf(0.5f, __cosf(d * 0.6041515809446141f), 0.5f) : 0.0f;
        pd[cb][lh] = make_float4(dx, dy, dz, d);
        pf[cb][lh] = make_float4(rinv, fca, fcr4, 0.0f);
        pvalid = fca > 0.0f;
    }
    // half-wave compaction via wave ballot
    const unsigned long long vm = __ballot(pvalid);
    const unsigned vmh = (unsigned)((vm >> (32 * h)) & 0xFFFFull);
    const int V = __popc(vmh);
    if (pvalid) {
        int idx = __popc(vmh & ((1u << lh) - 1u));
        vlist[cb][idx] = lh | (spl << 4);
    }
    // per-half species masks for radial gather
    const unsigned long long b0 = __ballot(lh < 16 && spl == 0);
    const unsigned long long b1 = __ballot(lh < 16 && spl == 1);
    const unsigned long long b2 = __ballot(lh < 16 && spl == 2);
    const unsigned long long b3 = __ballot(lh < 16 && spl == 3);
    const unsigned sm0 = (unsigned)((b0 >> (32 * h)) & 0xFFFFull);
    const unsigned sm1 = (unsigned)((b1 >> (32 * h)) & 0xFFFFull);
    const unsigned sm2 = (unsigned)((b2 >> (32 * h)) & 0xFFFFull);
    const unsigned sm3 = (unsigned)((b3 >> (32 * h)) & 0xFFFFull);

    // ---- radial staging: lane = (jj, rg), 8 shifts each ----
    {
        const int jj = lh & 15, rg = lh >> 4;   // rg 0/1
        float d = pd[cb][jj].w;
        float fcr4 = pf[cb][jj].z;
        #pragma unroll
        for (int rr = 0; rr < 8; ++rr) {
            int r = rg * 8 + rr;
            float e = d - (0.9f + 0.26875f * (float)r);
            rad[cb][jj][r] = fcr4 * __expf(-16.0f * e * e);
        }
    }

    // ---- triple phase: nt = V(V-1)/2 slots over 32 lanes, 4 static slots ----
    const int nt = (V * (V - 1)) >> 1;
    const int tw = 2 * V - 1;
    float caS[4], saS[4], t0S[4], r1S[4];
    int pS[4];
    #pragma unroll
    for (int slot = 0; slot < 4; ++slot) {
        pS[slot] = -1;
        const int s = slot * 32 + lh;
        if (s < nt) {
            float disc = (float)(tw * tw - 8 * s);
            int aa = (int)floorf(0.5f * ((float)tw - sqrtf(disc)));
            aa = aa < 0 ? 0 : (aa > V - 2 ? V - 2 : aa);
            int offa = (aa * (2 * V - 1 - aa)) >> 1;
            if (s < offa) { --aa; offa = (aa * (2 * V - 1 - aa)) >> 1; }
            else { int offn = ((aa + 1) * (2 * V - 2 - aa)) >> 1; if (s >= offn) { ++aa; offa = offn; } }
            const int bb = aa + 1 + (s - offa);
            const int va = vlist[cb][aa], vb = vlist[cb][bb];
            const int j = va & 15, spj = va >> 4;
            const int k = vb & 15, spk = vb >> 4;
            float4 Pj = pd[cb][j], Pk = pd[cb][k];
            float4 Fj = pf[cb][j], Fk = pf[cb][k];
            float dot = Pj.x * Pk.x + Pj.y * Pk.y + Pj.z * Pk.z;
            float ca = 0.95f * dot * Fj.x * Fk.x;
            ca = fminf(0.95f, fmaxf(-0.95f, ca));
            float s2 = 1.0f - ca * ca;                 // >= 0.0975
            float sa = s2 * __frsqrt_rn(s2);
            float davg = 0.5f * (Pj.w + Pk.w);
            float e0 = davg - 0.9f;
            float t0 = 2.0f * Fj.y * Fk.y * __expf(-8.0f * e0 * e0);
            float r1 = __expf(10.4f * davg - 12.74f);
            int lo = spj < spk ? spj : spk, hi = spj < spk ? spk : spj;
            int p = lo * 4 + hi - ((lo * (lo + 1)) >> 1);
            atomicAdd(&hist[cb][p], 1);
            caS[slot] = ca; saS[slot] = sa; t0S[slot] = t0; r1S[slot] = r1; pS[slot] = p;
        }
    }

    // ---- exclusive prefix over 10 buckets (half-private) ----
    if (lh < 10) {
        int sum = 0;
        for (int qq = 0; qq < lh; ++qq) sum += hist[cb][qq];
        sBase[cb][lh] = sum;
        sCur[cb][lh] = sum;
    }

    // ---- bucket fill ----
    #pragma unroll
    for (int slot = 0; slot < 4; ++slot) {
        if (pS[slot] >= 0) {
            int idx = atomicAdd(&sCur[cb][pS[slot]], 1);
            ebuf[cb][idx] = make_float4(caS[slot], saS[slot], t0S[slot], r1S[slot]);
        }
    }

    // ---- phase B: angular gather; lane lh = feature f, loop all 10 buckets ----
    float* base_o = out + (size_t)nmol * 16 + (size_t)(b * 16 + i) * 384;
    {
        const bool a1 = (a & 1), a2 = (a & 2) != 0;
        #pragma unroll
        for (int p = 0; p < 10; ++p) {
            int st = sBase[cb][p];
            int n = hist[cb][p];
            float acc = 0.0f;
            for (int e = 0; e < n; ++e) {
                float4 v = ebuf[cb][st + e];
                float c1 = fmaf(czh, v.x, fmaf(szh, v.y, 0.5f));  // (1+cos(th-shfz))/2
                float c2 = c1 * c1;
                float c4 = c2 * c2;
                float c8 = c4 * c4;
                float c16 = c8 * c8;
                float c32 = c16 * c16;
                float tt = v.z;
                float rsq = v.w * v.w;
                tt = a1 ? tt * v.w : tt;
                tt = a2 ? tt * rsq : tt;                           // tt = t0 * r1^a
                acc = fmaf(tt, c32, acc);
            }
            base_o[64 + p * 32 + lh] = acc * ga;
        }
    }

    // ---- phase R: radial gather; 2 passes: lane = (s_, r_) ----
    #pragma unroll
    for (int pass = 0; pass < 2; ++pass) {
        const int s_ = pass * 2 + (lh >> 4), r_ = lh & 15;
        unsigned m = s_ < 2 ? (s_ == 0 ? sm0 : sm1) : (s_ == 2 ? sm2 : sm3);
        float rv = 0.0f;
        while (m) {
            int jj = __ffs(m) - 1;
            m &= m - 1;
            rv += rad[cb][jj][r_];
        }
        base_o[s_ * 16 + r_] = rv;
    }
}

extern "C" void kernel_launch(void* const* d_in, const int* in_sizes, int n_in,
                              void* d_out, int out_size, void* d_ws, size_t ws_size,
                              hipStream_t stream) {
    const int*   species = (const int*)d_in[0];
    const float* coords  = (const float*)d_in[1];
    float*       out     = (float*)d_out;
    int nmol = in_sizes[0] / 16;   // 512
    aev_kernel<<<nmol * 2, 256, 0, stream>>>(species, coords, out, nmol);
}